// Round 9
// baseline (361.034 us; speedup 1.0000x reference)
//
#include <hip/hip_runtime.h>
#include <cstdint>

#define V_ 25
#define T_ 128
#define VT_ 3200
#define NVTF_ 204800.0f

typedef unsigned short ushort_t;
typedef __attribute__((ext_vector_type(8))) short s16x8;
typedef __attribute__((ext_vector_type(4))) float f32x4;

__device__ __forceinline__ ushort_t f2bf(float f) {
    union { float f; unsigned u; } v; v.f = f;
    unsigned r = v.u + 0x7FFFu + ((v.u >> 16) & 1u);
    return (ushort_t)(r >> 16);
}
__device__ __forceinline__ float bf2f(ushort_t h) {
    union { unsigned u; float f; } v; v.u = ((unsigned)h) << 16;
    return v.f;
}
__device__ __forceinline__ unsigned cvtpk(float lo, float hi) {
    unsigned r;
    asm volatile("v_cvt_pk_bf16_f32 %0, %1, %2" : "=v"(r) : "v"(lo), "v"(hi));
    return r;
}
__device__ __forceinline__ void gload16(const void* g, void* l) {
    __builtin_amdgcn_global_load_lds((const __attribute__((address_space(1))) void*)g,
                                     (__attribute__((address_space(3))) void*)l, 16, 0, 0);
}

// ---------------- k_a: a1/a2 = wg @ x + xb bf16 [v*T+t][64] + fused wcat ----------------
__global__ __launch_bounds__(128) void k_a(const float* __restrict__ x,
        const float* __restrict__ wg1, const float* __restrict__ wg2,
        ushort_t* __restrict__ a1, ushort_t* __restrict__ a2,
        ushort_t* __restrict__ xb,
        const float* __restrict__ w11, const float* __restrict__ w12,
        const float* __restrict__ w21, const float* __restrict__ w22,
        const float* __restrict__ w31, const float* __restrict__ w32,
        ushort_t* __restrict__ Wc) {
    int b = blockIdx.x; int n = b / V_; int v = b % V_;
    int t = threadIdx.x;
    // fused weight concat (90112 items over 204800 threads)
    int wi = b * 128 + t;
    if (wi < 90112) {
        float wv;
        if (wi < 8192) {
            int o = wi >> 7, k = wi & 127;
            wv = (k < 64) ? w11[o * 64 + k] : w12[o * 64 + k - 64];
        } else if (wi < 24576) {
            int j = wi - 8192; int o = j >> 7, k = j & 127;
            wv = (k < 64) ? w21[o * 64 + k] : w22[o * 64 + k - 64];
        } else {
            int j = wi - 24576; int o = j >> 8, k = j & 255;
            wv = (k < 128) ? w31[o * 128 + k] : w32[o * 128 + k - 128];
        }
        Wc[wi] = f2bf(wv);
    }
    __shared__ float w1s[1024], w2s[1024];
    for (int i = threadIdx.x; i < 1024; i += 128) { w1s[i] = wg1[i]; w2s[i] = wg2[i]; }
    __syncthreads();
    float s1[16], s2[16];
    #pragma unroll
    for (int o = 0; o < 16; o++) { s1[o] = 0.f; s2[o] = 0.f; }
    s16x8 xs[8];
    const float* xp = x + (size_t)n * 204800 + v * T_ + t;
    #pragma unroll
    for (int c = 0; c < 64; c++) {
        float xv = xp[(size_t)c * VT_];
        xs[c >> 3][c & 7] = (short)f2bf(xv);
        #pragma unroll
        for (int o = 0; o < 16; o++) {
            s1[o] = fmaf(w1s[o*64+c], xv, s1[o]);
            s2[o] = fmaf(w2s[o*64+c], xv, s2[o]);
        }
    }
    size_t abase = (size_t)n * 51200 + v * T_ + t;
    #pragma unroll
    for (int o = 0; o < 16; o++) {
        a1[abase + (size_t)o * VT_] = f2bf(s1[o]);
        a2[abase + (size_t)o * VT_] = f2bf(s2[o]);
    }
    ushort_t* cp = xb + (size_t)(n * VT_ + v * T_ + t) * 64;
    #pragma unroll
    for (int ch = 0; ch < 8; ch++) *(s16x8*)(cp + ch * 8) = xs[ch];
}

// ---------------- k_g: g = softmax(a1^T a2), fp32 (d_out) + bf16 copy [n][t][v][32] ----------------
__global__ __launch_bounds__(256) void k_g(const ushort_t* __restrict__ a1,
        const ushort_t* __restrict__ a2, float* __restrict__ g,
        ushort_t* __restrict__ gb) {
    int n = blockIdx.x >> 3; int t0 = (blockIdx.x & 7) * 16;
    __shared__ float A1s[6400], A2s[6400]; // [o][v][tt]
    for (int i = threadIdx.x; i < 6400; i += 256) {
        int o = i / 400; int r = i % 400; int v = r >> 4; int tt = r & 15;
        size_t ga = (size_t)n * 51200 + (size_t)o * VT_ + v * T_ + t0 + tt;
        A1s[i] = bf2f(a1[ga]);
        A2s[i] = bf2f(a2[ga]);
    }
    __syncthreads();
    for (int r = threadIdx.x; r < 400; r += 256) {
        int v = r >> 4; int tt = r & 15;
        float a1r[16];
        #pragma unroll
        for (int o = 0; o < 16; o++) a1r[o] = A1s[o*400 + v*16 + tt];
        float gr[25];
        float mx = -1e30f;
        for (int u = 0; u < 25; u++) {
            float s = 0.f;
            #pragma unroll
            for (int o = 0; o < 16; o++) s = fmaf(a1r[o], A2s[o*400 + u*16 + tt], s);
            gr[u] = s; mx = fmaxf(mx, s);
        }
        float sum = 0.f;
        for (int u = 0; u < 25; u++) { gr[u] = __expf(gr[u] - mx); sum += gr[u]; }
        float inv = 1.f / sum;
        float* gp = g + ((size_t)(n * T_ + t0 + tt) * V_ + v) * V_;
        ushort_t* gbp = gb + ((size_t)((n * 128 + t0 + tt) * 25 + v)) * 32;
        for (int u = 0; u < 25; u++) {
            float val = gr[u] * inv;
            gp[u] = val;
            gbp[u] = f2bf(val);
        }
    }
}

// ---------------- fused [BN+ReLU] + MP + MFMA GEMM, TGROUPS=2 (MROWS=50) ----------------
template<int C, bool BNB, bool XBSRC, int TOUT, int OPASS>
__global__ __launch_bounds__(256) void k_fgemm(
        const ushort_t* __restrict__ Wc, const ushort_t* __restrict__ ysrc,
        const ushort_t* __restrict__ gb,
        const float* __restrict__ bns, const float* __restrict__ bnb,
        ushort_t* __restrict__ yt,
        float* __restrict__ psum, float* __restrict__ psq) {
    constexpr int K2 = 2 * C;
    constexpr int KSTEPS = K2 / 32;   // 4 or 8
    constexpr int NC8 = C / 8;        // 8 or 16
    constexpr int HKS = C / 32;       // 2 or 4
    constexpr int TG = 2;
    constexpr int MROWS = 50;
    constexpr int MI = 4;             // 64 rows, mask >= 50
    constexpr int VSPLIT = 128 / C;   // 2 (C=64) or 1 (C=128)
    constexpr int GSB = TG * 25 * 28 * 4;       // 5600
    constexpr int XBYTES = (TOUT == 0) ? (MROWS * 72 * 2) : GSB; // 7200 / 5600
    __shared__ __align__(16) ushort_t YS[MROWS * C];
    __shared__ __align__(16) ushort_t MPo[MROWS * C];
    __shared__ __align__(16) char XTRA[XBYTES];
    float* GS = (float*)XTRA;          // [2 tl][25 u][28] f32 (g transposed)
    ushort_t* Lw = (ushort_t*)XTRA;    // TOUT==0 epilogue (GS dead then)

    int n = blockIdx.y, mb = blockIdx.x;
    int m0 = mb * MROWS, tb = mb * TG;
    int tid = threadIdx.x, w = tid >> 6, lane = tid & 63;
    int l15 = lane & 15, g4 = lane >> 4;

    // ---- stage GS ----
    for (int i = tid; i < TG * 625; i += 256) {
        int tl = i / 625, r = i % 625, u = r / 25, v = r % 25;
        GS[(tl * 25 + u) * 28 + v] =
            bf2f(gb[((size_t)((n * 128 + tb + tl) * 25 + v)) * 32 + u]);
    }
    // ---- stage Y (+BN+ReLU) -> YS swizzled ----
    for (int i = tid; i < MROWS * NC8; i += 256) {
        int yr = i / NC8, cc = i % NC8;
        size_t saddr;
        if (XBSRC) {
            int t = tb + yr / 25, v = yr % 25;
            saddr = (size_t)n * 204800 + (size_t)(v * 128 + t) * 64 + cc * 8;
        } else {
            saddr = ((size_t)n * VT_ + m0 + yr) * C + cc * 8;
        }
        s16x8 vv = *(const s16x8*)(ysrc + saddr);
        if (BNB) {
            int ob = cc * 8;
            float4 s0 = *(const float4*)(bns + ob), s1 = *(const float4*)(bns + ob + 4);
            float4 h0 = *(const float4*)(bnb + ob), h1 = *(const float4*)(bnb + ob + 4);
            float sc[8] = {s0.x, s0.y, s0.z, s0.w, s1.x, s1.y, s1.z, s1.w};
            float sh[8] = {h0.x, h0.y, h0.z, h0.w, h1.x, h1.y, h1.z, h1.w};
            float ff[8];
            #pragma unroll
            for (int j = 0; j < 8; j++)
                ff[j] = fmaxf(fmaf(bf2f((ushort_t)vv[j]), sc[j], sh[j]), 0.f);
            union { unsigned u[4]; s16x8 s; } U;
            U.u[0] = cvtpk(ff[0], ff[1]); U.u[1] = cvtpk(ff[2], ff[3]);
            U.u[2] = cvtpk(ff[4], ff[5]); U.u[3] = cvtpk(ff[6], ff[7]);
            vv = U.s;
        }
        *(s16x8*)(YS + ((size_t)yr * NC8 + (cc ^ (yr & 7))) * 8) = vv;
    }
    __syncthreads();
    // ---- MP: unit = (tl, col[, v-half]); amortized over v ----
    {
        int tl = tid >> 7;
        int rem = tid & 127;
        int col = rem % C;
        int hv = (VSPLIT == 2) ? (rem / C) : 0;
        int c8 = col >> 3, sub = col & 7;
        constexpr int VN = (VSPLIT == 2) ? 13 : 25;
        int v0 = hv * 12;                      // hv0: v0..11 (12), hv1: v12..24 (13)
        int vcnt = (VSPLIT == 2) ? (hv ? 13 : 12) : 25;
        float macc[VN];
        #pragma unroll
        for (int j = 0; j < VN; j++) macc[j] = 0.f;
        for (int u = 0; u < 25; u++) {
            int yr = tl * 25 + u;
            float yf = bf2f(YS[((size_t)yr * NC8 + (c8 ^ (yr & 7))) * 8 + sub]);
            const float* gp = &GS[(tl * 25 + u) * 28] + v0;
            if (VSPLIT == 1) {
                #pragma unroll
                for (int q = 0; q < 6; q++) {
                    float4 gq = *(const float4*)(gp + q * 4);
                    macc[q*4+0] = fmaf(gq.x, yf, macc[q*4+0]);
                    macc[q*4+1] = fmaf(gq.y, yf, macc[q*4+1]);
                    macc[q*4+2] = fmaf(gq.z, yf, macc[q*4+2]);
                    macc[q*4+3] = fmaf(gq.w, yf, macc[q*4+3]);
                }
                macc[24] = fmaf(gp[24], yf, macc[24]);
            } else {
                #pragma unroll
                for (int q = 0; q < 3; q++) {
                    float4 gq = *(const float4*)(gp + q * 4);
                    macc[q*4+0] = fmaf(gq.x, yf, macc[q*4+0]);
                    macc[q*4+1] = fmaf(gq.y, yf, macc[q*4+1]);
                    macc[q*4+2] = fmaf(gq.z, yf, macc[q*4+2]);
                    macc[q*4+3] = fmaf(gq.w, yf, macc[q*4+3]);
                }
                if (hv) macc[12] = fmaf(gp[12], yf, macc[12]);
            }
        }
        #pragma unroll
        for (int j = 0; j < VN; j++) {
            if (j < vcnt) {
                int r = tl * 25 + v0 + j;
                MPo[((size_t)r * NC8 + (c8 ^ (r & 7))) * 8 + sub] = f2bf(macc[j]);
            }
        }
    }
    __syncthreads();
    // ---- o-pass sweep: A in registers, MFMA, stats, epilogue ----
    for (int pass = 0; pass < OPASS; pass++) {
        int o0 = pass * 64;
        s16x8 aReg[KSTEPS];
        const ushort_t* ap = Wc + (size_t)(o0 + w * 16 + l15) * K2 + g4 * 8;
        #pragma unroll
        for (int ks = 0; ks < KSTEPS; ks++)
            aReg[ks] = *(const s16x8*)(ap + ks * 32);
        f32x4 acc[MI] = {};
        __builtin_amdgcn_s_setprio(1);
        #pragma unroll
        for (int ks = 0; ks < KSTEPS; ks++) {
            const ushort_t* bbase = (ks < HKS) ? MPo : YS;
            int ksl = (ks < HKS) ? ks : ks - HKS;
            #pragma unroll
            for (int mi = 0; mi < MI; mi++) {
                int r = mi * 16 + l15;
                int rr = (r < MROWS) ? r : (MROWS - 1);
                int ch = ksl * 4 + g4;
                s16x8 bF = *(const s16x8*)(bbase + ((size_t)rr * NC8 + (ch ^ (rr & 7))) * 8);
                acc[mi] = __builtin_amdgcn_mfma_f32_16x16x32_bf16(aReg[ks], bF, acc[mi], 0, 0, 0);
            }
        }
        __builtin_amdgcn_s_setprio(0);
        // BN partial stats (mask rows >= 50: mi==3 && l15>=2)
        int p = n * 64 + mb;
        #pragma unroll
        for (int b = 0; b < 4; b++) {
            float ss = 0.f, qq = 0.f;
            #pragma unroll
            for (int mi = 0; mi < MI; mi++) {
                float v0 = acc[mi][b];
                if (mi == 3 && l15 >= 2) v0 = 0.f;
                ss += v0; qq = fmaf(v0, v0, qq);
            }
            #pragma unroll
            for (int msk = 1; msk < 16; msk <<= 1) {
                ss += __shfl_xor(ss, msk, 16);
                qq += __shfl_xor(qq, msk, 16);
            }
            if (l15 == 0) {
                int o = o0 + w * 16 + g4 * 4 + b;
                psum[(size_t)o * 4096 + p] = ss;
                psq [(size_t)o * 4096 + p] = qq;
            }
        }
        if (TOUT == 0) {
            __syncthreads();
            #pragma unroll
            for (int mi = 0; mi < MI; mi++) {
                int r = mi * 16 + l15;
                if (r < MROWS) {
                    unsigned lo = cvtpk(acc[mi][0], acc[mi][1]);
                    unsigned hi = cvtpk(acc[mi][2], acc[mi][3]);
                    *(unsigned*)(Lw + r * 72 + w * 16 + g4 * 4)     = lo;
                    *(unsigned*)(Lw + r * 72 + w * 16 + g4 * 4 + 2) = hi;
                }
            }
            __syncthreads();
            for (int i = tid; i < MROWS * 8; i += 256) {
                int r = i >> 3, oc = i & 7;
                s16x8 pk = *(const s16x8*)(Lw + r * 72 + oc * 8);
                *(s16x8*)(yt + ((size_t)n * VT_ + m0 + r) * (OPASS * 64) + o0 + oc * 8) = pk;
            }
        } else {
            int obase = n * 256 + o0 + w * 16 + g4 * 4;
            #pragma unroll
            for (int mi = 0; mi < MI; mi++) {
                int r = mi * 16 + l15;
                if (r < MROWS) {
                    #pragma unroll
                    for (int b = 0; b < 4; b++)
                        yt[(size_t)(obase + b) * VT_ + m0 + r] = f2bf(acc[mi][b]);
                }
            }
        }
    }
}

// ---------------- finalize per-channel stats -> scale/shift arrays ----------------
__global__ __launch_bounds__(256) void k_stats(const float* __restrict__ psum,
        const float* __restrict__ psq, const float* __restrict__ gamma,
        const float* __restrict__ beta, float* __restrict__ bns,
        float* __restrict__ bnb) {
    int o = blockIdx.x;
    float s = 0.f, q = 0.f;
    for (int i = threadIdx.x; i < 4096; i += 256) {
        s += psum[(size_t)o*4096+i]; q += psq[(size_t)o*4096+i];
    }
    __shared__ float rs[256], rq[256];
    rs[threadIdx.x] = s; rq[threadIdx.x] = q;
    __syncthreads();
    for (int st = 128; st > 0; st >>= 1) {
        if (threadIdx.x < st) { rs[threadIdx.x] += rs[threadIdx.x+st]; rq[threadIdx.x] += rq[threadIdx.x+st]; }
        __syncthreads();
    }
    if (threadIdx.x == 0) {
        float mean = rs[0] / NVTF_;
        float var = rq[0] / NVTF_ - mean * mean;
        float scale = gamma[o] * rsqrtf(var + 1e-5f);
        bns[o] = scale;
        bnb[o] = beta[o] - mean * scale;
    }
}

// ---------------- final BN+ReLU + (t,v)->(v,t) transpose: y3 [O][m'] -> fp32 xout ----------------
__global__ __launch_bounds__(256) void k_bnf(const ushort_t* __restrict__ y3,
        const float* __restrict__ bns, const float* __restrict__ bnb,
        float* __restrict__ xout) {
    __shared__ __align__(16) ushort_t L[8 * VT_];
    int n = blockIdx.y, oc = blockIdx.x;   // 64 x 32
    size_t base = (size_t)(n * 256 + oc * 8) * VT_;
    for (int i = threadIdx.x; i < 3200; i += 256)
        gload16(y3 + base + (size_t)i * 8, (char*)L + i * 16);
    __syncthreads();
    for (int i = threadIdx.x; i < 6400; i += 256) {
        int t4 = i & 31, v = (i >> 5) % 25, o = i / 800;
        int og = oc * 8 + o;
        float sc = bns[og], sh = bnb[og];
        int lb = o * VT_ + v;
        float4 f;
        f.x = fmaxf(fmaf(bf2f(L[lb + (t4*4+0)*25]), sc, sh), 0.f);
        f.y = fmaxf(fmaf(bf2f(L[lb + (t4*4+1)*25]), sc, sh), 0.f);
        f.z = fmaxf(fmaf(bf2f(L[lb + (t4*4+2)*25]), sc, sh), 0.f);
        f.w = fmaxf(fmaf(bf2f(L[lb + (t4*4+3)*25]), sc, sh), 0.f);
        *(float4*)(xout + (size_t)(n * 256 + og) * VT_ + v * T_ + t4 * 4) = f;
    }
}

extern "C" void kernel_launch(void* const* d_in, const int* in_sizes, int n_in,
                              void* d_out, int out_size, void* d_ws, size_t ws_size,
                              hipStream_t stream) {
    const float* x   = (const float*)d_in[0];
    const float* wg1 = (const float*)d_in[1];
    const float* wg2 = (const float*)d_in[2];
    const float* w11 = (const float*)d_in[3];
    const float* w12 = (const float*)d_in[4];
    const float* ga1 = (const float*)d_in[5];
    const float* be1 = (const float*)d_in[6];
    const float* w21 = (const float*)d_in[7];
    const float* w22 = (const float*)d_in[8];
    const float* ga2 = (const float*)d_in[9];
    const float* be2 = (const float*)d_in[10];
    const float* w31 = (const float*)d_in[11];
    const float* w32 = (const float*)d_in[12];
    const float* ga3 = (const float*)d_in[13];
    const float* be3 = (const float*)d_in[14];

    float* xout = (float*)d_out;               // (64,256,25,128) fp32
    float* gout = xout + 52428800;             // (64,128,25,25) fp32

    float* ws = (float*)d_ws;
    ushort_t* xb  = (ushort_t*)(ws + 0);          // 13,107,200 us [v*T+t][64]
    ushort_t* a1  = (ushort_t*)(ws + 6553600);    // 3,276,800 us
    ushort_t* a2  = (ushort_t*)(ws + 8192000);    // 3,276,800 us
    ushort_t* y1  = (ushort_t*)(ws + 9830400);    // 13,107,200 us [m'][64]
    ushort_t* y2  = (ushort_t*)(ws + 16384000);   // 26,214,400 us [m'][128]
    ushort_t* y3  = (ushort_t*)(ws + 29491200);   // 52,428,800 us [O=256][m']
    ushort_t* gb  = (ushort_t*)(ws + 55705600);   // 6,553,600 us [n][t][v][32]
    float* psum = ws + 58982400;                  // 1,048,576 fl [o][4096]
    float* psq  = ws + 60030976;                  // 1,048,576 fl
    ushort_t* Wc = (ushort_t*)(ws + 61079552);    // 90,112 us
    float* bns  = ws + 61124608;                  // 256 fl
    float* bnb  = ws + 61124864;                  // 256 fl
    ushort_t* Wc1 = Wc, *Wc2 = Wc + 8192, *Wc3 = Wc + 24576;

    k_a<<<1600, 128, 0, stream>>>(x, wg1, wg2, a1, a2, xb,
                                  w11, w12, w21, w22, w31, w32, Wc);
    k_g<<<512, 256, 0, stream>>>(a1, a2, gout, gb);

    // layer 1: C=64 -> O=64 (xb source, no BN)
    k_fgemm<64, false, true, 0, 1><<<dim3(64, 64), 256, 0, stream>>>(
        Wc1, xb, gb, nullptr, nullptr, y1, psum, psq);
    k_stats<<<64, 256, 0, stream>>>(psum, psq, ga1, be1, bns, bnb);

    // layer 2: C=64 -> O=128 (BN(y1) fused)
    k_fgemm<64, true, false, 0, 2><<<dim3(64, 64), 256, 0, stream>>>(
        Wc2, y1, gb, bns, bnb, y2, psum, psq);
    k_stats<<<128, 256, 0, stream>>>(psum, psq, ga2, be2, bns, bnb);

    // layer 3: C=128 -> O=256 (BN(y2) fused), output [O][m'] direct stores
    k_fgemm<128, true, false, 2, 4><<<dim3(64, 64), 256, 0, stream>>>(
        Wc3, y2, gb, bns, bnb, y3, psum, psq);
    k_stats<<<256, 256, 0, stream>>>(psum, psq, ga3, be3, bns, bnb);

    k_bnf<<<dim3(32, 64), 256, 0, stream>>>(y3, bns, bnb, xout);
}

// Round 10
// 347.754 us; speedup vs baseline: 1.0382x; 1.0382x over previous
//
#include <hip/hip_runtime.h>
#include <cstdint>

#define V_ 25
#define T_ 128
#define VT_ 3200
#define NVTF_ 204800.0f

typedef unsigned short ushort_t;
typedef __attribute__((ext_vector_type(8))) short s16x8;
typedef __attribute__((ext_vector_type(4))) short s16x4;
typedef __attribute__((ext_vector_type(4))) float f32x4;

__device__ __forceinline__ ushort_t f2bf(float f) {
    union { float f; unsigned u; } v; v.f = f;
    unsigned r = v.u + 0x7FFFu + ((v.u >> 16) & 1u);
    return (ushort_t)(r >> 16);
}
__device__ __forceinline__ float bf2f(ushort_t h) {
    union { unsigned u; float f; } v; v.u = ((unsigned)h) << 16;
    return v.f;
}
__device__ __forceinline__ unsigned cvtpk(float lo, float hi) {
    unsigned r;
    asm volatile("v_cvt_pk_bf16_f32 %0, %1, %2" : "=v"(r) : "v"(lo), "v"(hi));
    return r;
}
__device__ __forceinline__ void gload16(const void* g, void* l) {
    __builtin_amdgcn_global_load_lds((const __attribute__((address_space(1))) void*)g,
                                     (__attribute__((address_space(3))) void*)l, 16, 0, 0);
}

// ---------------- k_a: a1/a2 = wg @ x + xb bf16 [v*T+t][64] + fused wcat ----------------
__global__ __launch_bounds__(128) void k_a(const float* __restrict__ x,
        const float* __restrict__ wg1, const float* __restrict__ wg2,
        ushort_t* __restrict__ a1, ushort_t* __restrict__ a2,
        ushort_t* __restrict__ xb,
        const float* __restrict__ w11, const float* __restrict__ w12,
        const float* __restrict__ w21, const float* __restrict__ w22,
        const float* __restrict__ w31, const float* __restrict__ w32,
        ushort_t* __restrict__ Wc) {
    int b = blockIdx.x; int n = b / V_; int v = b % V_;
    int t = threadIdx.x;
    int wi = b * 128 + t;
    if (wi < 90112) {
        float wv;
        if (wi < 8192) {
            int o = wi >> 7, k = wi & 127;
            wv = (k < 64) ? w11[o * 64 + k] : w12[o * 64 + k - 64];
        } else if (wi < 24576) {
            int j = wi - 8192; int o = j >> 7, k = j & 127;
            wv = (k < 64) ? w21[o * 64 + k] : w22[o * 64 + k - 64];
        } else {
            int j = wi - 24576; int o = j >> 8, k = j & 255;
            wv = (k < 128) ? w31[o * 128 + k] : w32[o * 128 + k - 128];
        }
        Wc[wi] = f2bf(wv);
    }
    __shared__ float w1s[1024], w2s[1024];
    for (int i = threadIdx.x; i < 1024; i += 128) { w1s[i] = wg1[i]; w2s[i] = wg2[i]; }
    __syncthreads();
    float s1[16], s2[16];
    #pragma unroll
    for (int o = 0; o < 16; o++) { s1[o] = 0.f; s2[o] = 0.f; }
    s16x8 xs[8];
    const float* xp = x + (size_t)n * 204800 + v * T_ + t;
    #pragma unroll
    for (int c = 0; c < 64; c++) {
        float xv = xp[(size_t)c * VT_];
        xs[c >> 3][c & 7] = (short)f2bf(xv);
        #pragma unroll
        for (int o = 0; o < 16; o++) {
            s1[o] = fmaf(w1s[o*64+c], xv, s1[o]);
            s2[o] = fmaf(w2s[o*64+c], xv, s2[o]);
        }
    }
    size_t abase = (size_t)n * 51200 + v * T_ + t;
    #pragma unroll
    for (int o = 0; o < 16; o++) {
        a1[abase + (size_t)o * VT_] = f2bf(s1[o]);
        a2[abase + (size_t)o * VT_] = f2bf(s2[o]);
    }
    ushort_t* cp = xb + (size_t)(n * VT_ + v * T_ + t) * 64;
    #pragma unroll
    for (int ch = 0; ch < 8; ch++) *(s16x8*)(cp + ch * 8) = xs[ch];
}

// ---------------- k_g: g = softmax(a1^T a2), fp32 (d_out) + bf16 copy [n][t][v][32] ----------------
__global__ __launch_bounds__(256) void k_g(const ushort_t* __restrict__ a1,
        const ushort_t* __restrict__ a2, float* __restrict__ g,
        ushort_t* __restrict__ gb) {
    int n = blockIdx.x >> 3; int t0 = (blockIdx.x & 7) * 16;
    __shared__ float A1s[6400], A2s[6400]; // [o][v][tt]
    for (int i = threadIdx.x; i < 6400; i += 256) {
        int o = i / 400; int r = i % 400; int v = r >> 4; int tt = r & 15;
        size_t ga = (size_t)n * 51200 + (size_t)o * VT_ + v * T_ + t0 + tt;
        A1s[i] = bf2f(a1[ga]);
        A2s[i] = bf2f(a2[ga]);
    }
    __syncthreads();
    for (int r = threadIdx.x; r < 400; r += 256) {
        int v = r >> 4; int tt = r & 15;
        float a1r[16];
        #pragma unroll
        for (int o = 0; o < 16; o++) a1r[o] = A1s[o*400 + v*16 + tt];
        float gr[25];
        float mx = -1e30f;
        for (int u = 0; u < 25; u++) {
            float s = 0.f;
            #pragma unroll
            for (int o = 0; o < 16; o++) s = fmaf(a1r[o], A2s[o*400 + u*16 + tt], s);
            gr[u] = s; mx = fmaxf(mx, s);
        }
        float sum = 0.f;
        for (int u = 0; u < 25; u++) { gr[u] = __expf(gr[u] - mx); sum += gr[u]; }
        float inv = 1.f / sum;
        float* gp = g + ((size_t)(n * T_ + t0 + tt) * V_ + v) * V_;
        ushort_t* gbp = gb + ((size_t)((n * 128 + t0 + tt) * 25 + v)) * 32;
        for (int u = 0; u < 25; u++) {
            float val = gr[u] * inv;
            gp[u] = val;
            gbp[u] = f2bf(val);
        }
    }
}

// ---------------- fused [BN+ReLU] + MP + MFMA GEMM, TG=4, MROWS=100 ----------------
template<int C, bool BNB, bool XBSRC, int TOUT, int OPASS>
__global__ __launch_bounds__(256) void k_fgemm(
        const ushort_t* __restrict__ Wc, const ushort_t* __restrict__ ysrc,
        const ushort_t* __restrict__ gb,
        const float* __restrict__ bns, const float* __restrict__ bnb,
        ushort_t* __restrict__ yt,
        float* __restrict__ psum, float* __restrict__ psq) {
    constexpr int K2 = 2 * C;
    constexpr int KSTEPS = K2 / 32;   // 4 or 8
    constexpr int NC8 = C / 8;        // 8 or 16
    constexpr int HKS = C / 32;       // 2 or 4
    constexpr int MROWS = 100;
    constexpr int MI = 7;
    constexpr int CW = (C == 64) ? 1 : 2;  // bf16 per MP unit-chunk
    constexpr int XBYTES = (TOUT == 0) ? 14400 : 13824; // max(GS 11200, Lw)
    __shared__ __align__(16) ushort_t YS[MROWS * C];
    __shared__ __align__(16) ushort_t MPo[MROWS * C];
    __shared__ __align__(16) char XTRA[XBYTES];
    float* GS = (float*)XTRA;          // [4 tl][25 u][28] f32 (g transposed)
    ushort_t* Lw = (ushort_t*)XTRA;    // epilogue restage (GS dead by then)

    int n = blockIdx.y, mb = blockIdx.x;
    int m0 = mb * MROWS, tb = mb * 4;
    int tid = threadIdx.x, w = tid >> 6, lane = tid & 63;
    int l15 = lane & 15, g4 = lane >> 4;

    // ---- stage GS: f32 transposed g ----
    for (int i = tid; i < 2500; i += 256) {
        int tl = i / 625, r = i % 625, u = r / 25, v = r % 25;
        GS[(tl * 25 + u) * 28 + v] =
            bf2f(gb[((size_t)((n * 128 + tb + tl) * 25 + v)) * 32 + u]);
    }
    // ---- stage Y (+BN+ReLU) -> YS swizzled ----
    for (int i = tid; i < MROWS * NC8; i += 256) {
        int yr = i / NC8, cc = i % NC8;
        size_t saddr;
        if (XBSRC) {
            int t = tb + yr / 25, v = yr % 25;
            saddr = (size_t)n * 204800 + (size_t)(v * 128 + t) * 64 + cc * 8;
        } else {
            saddr = ((size_t)n * VT_ + m0 + yr) * C + cc * 8;
        }
        s16x8 vv = *(const s16x8*)(ysrc + saddr);
        if (BNB) {
            int ob = cc * 8;
            float4 s0 = *(const float4*)(bns + ob), s1 = *(const float4*)(bns + ob + 4);
            float4 h0 = *(const float4*)(bnb + ob), h1 = *(const float4*)(bnb + ob + 4);
            float sc[8] = {s0.x, s0.y, s0.z, s0.w, s1.x, s1.y, s1.z, s1.w};
            float sh[8] = {h0.x, h0.y, h0.z, h0.w, h1.x, h1.y, h1.z, h1.w};
            float ff[8];
            #pragma unroll
            for (int j = 0; j < 8; j++)
                ff[j] = fmaxf(fmaf(bf2f((ushort_t)vv[j]), sc[j], sh[j]), 0.f);
            union { unsigned u[4]; s16x8 s; } U;
            U.u[0] = cvtpk(ff[0], ff[1]); U.u[1] = cvtpk(ff[2], ff[3]);
            U.u[2] = cvtpk(ff[4], ff[5]); U.u[3] = cvtpk(ff[6], ff[7]);
            vv = U.s;
        }
        *(s16x8*)(YS + ((size_t)yr * NC8 + (cc ^ (yr & 7))) * 8) = vv;
    }
    __syncthreads();
    // ---- MP: unit = (tl = tid>>6, chunk cwi = tid&63), all 25 v amortized ----
    {
        int cwi = tid & 63;
        int tl = tid >> 6;
        int c8 = (cwi * CW) >> 3;
        int sub = (cwi * CW) & 7;
        float macc[25][CW];
        #pragma unroll
        for (int v = 0; v < 25; v++)
            #pragma unroll
            for (int k = 0; k < CW; k++) macc[v][k] = 0.f;
        for (int u = 0; u < 25; u++) {
            int yr = tl * 25 + u;
            const ushort_t* yp = YS + ((size_t)yr * NC8 + (c8 ^ (yr & 7))) * 8 + sub;
            float yf[CW];
            if (CW == 2) {
                unsigned yw = *(const unsigned*)yp;
                yf[0] = bf2f((ushort_t)(yw & 0xFFFFu));
                yf[1] = bf2f((ushort_t)(yw >> 16));
            } else {
                yf[0] = bf2f(*yp);
            }
            const float* gp = &GS[(tl * 25 + u) * 28];
            float gv[25];
            #pragma unroll
            for (int q = 0; q < 6; q++) {
                float4 gq = *(const float4*)(gp + q * 4);
                gv[q*4+0] = gq.x; gv[q*4+1] = gq.y; gv[q*4+2] = gq.z; gv[q*4+3] = gq.w;
            }
            gv[24] = gp[24];
            #pragma unroll
            for (int v = 0; v < 25; v++)
                #pragma unroll
                for (int k = 0; k < CW; k++)
                    macc[v][k] = fmaf(gv[v], yf[k], macc[v][k]);
        }
        #pragma unroll
        for (int v = 0; v < 25; v++) {
            int r = tl * 25 + v;
            ushort_t* op = MPo + ((size_t)r * NC8 + (c8 ^ (r & 7))) * 8 + sub;
            if (CW == 2) {
                *(unsigned*)op = cvtpk(macc[v][0], macc[v][1]);
            } else {
                *op = f2bf(macc[v][0]);
            }
        }
    }
    __syncthreads();
    // ---- o-pass sweep: A in registers, MFMA, stats, epilogue ----
    for (int pass = 0; pass < OPASS; pass++) {
        int o0 = pass * 64;
        s16x8 aReg[KSTEPS];
        const ushort_t* ap = Wc + (size_t)(o0 + w * 16 + l15) * K2 + g4 * 8;
        #pragma unroll
        for (int ks = 0; ks < KSTEPS; ks++)
            aReg[ks] = *(const s16x8*)(ap + ks * 32);
        f32x4 acc[MI] = {};
        __builtin_amdgcn_s_setprio(1);
        #pragma unroll
        for (int ks = 0; ks < KSTEPS; ks++) {
            const ushort_t* bbase = (ks < HKS) ? MPo : YS;
            int ksl = (ks < HKS) ? ks : ks - HKS;
            #pragma unroll
            for (int mi = 0; mi < MI; mi++) {
                int r = mi * 16 + l15;
                int rr = (r < MROWS) ? r : (MROWS - 1);
                int ch = ksl * 4 + g4;
                s16x8 bF = *(const s16x8*)(bbase + ((size_t)rr * NC8 + (ch ^ (rr & 7))) * 8);
                acc[mi] = __builtin_amdgcn_mfma_f32_16x16x32_bf16(aReg[ks], bF, acc[mi], 0, 0, 0);
            }
        }
        __builtin_amdgcn_s_setprio(0);
        // BN partial stats (mask pad rows >= 100: mi==6 && l15>=4)
        int p = n * 32 + mb;
        #pragma unroll
        for (int b = 0; b < 4; b++) {
            float ss = 0.f, qq = 0.f;
            #pragma unroll
            for (int mi = 0; mi < MI; mi++) {
                float v0 = acc[mi][b];
                if (mi == 6 && l15 >= 4) v0 = 0.f;
                ss += v0; qq = fmaf(v0, v0, qq);
            }
            #pragma unroll
            for (int msk = 1; msk < 16; msk <<= 1) {
                ss += __shfl_xor(ss, msk, 16);
                qq += __shfl_xor(qq, msk, 16);
            }
            if (l15 == 0) {
                int o = o0 + w * 16 + g4 * 4 + b;
                psum[(size_t)o * 2048 + p] = ss;
                psq [(size_t)o * 2048 + p] = qq;
            }
        }
        if (TOUT == 0) {
            __syncthreads();
            #pragma unroll
            for (int mi = 0; mi < MI; mi++) {
                int r = mi * 16 + l15;
                if (r < MROWS) {
                    unsigned lo = cvtpk(acc[mi][0], acc[mi][1]);
                    unsigned hi = cvtpk(acc[mi][2], acc[mi][3]);
                    *(unsigned*)(Lw + r * 72 + w * 16 + g4 * 4)     = lo;
                    *(unsigned*)(Lw + r * 72 + w * 16 + g4 * 4 + 2) = hi;
                }
            }
            __syncthreads();
            for (int i = tid; i < MROWS * 8; i += 256) {
                int r = i >> 3, oc = i & 7;
                s16x8 pk = *(const s16x8*)(Lw + r * 72 + oc * 8);
                *(s16x8*)(yt + ((size_t)n * VT_ + m0 + r) * (OPASS * 64) + o0 + oc * 8) = pk;
            }
        } else {
            // fg3: restage to Lw[64 o][108 m] then coalesced s16x4 stores to [O][m']
            __syncthreads();
            #pragma unroll
            for (int mi = 0; mi < MI; mi++) {
                int r = mi * 16 + l15;
                if (r < MROWS) {
                    int ol = w * 16 + g4 * 4;
                    Lw[(ol + 0) * 108 + r] = f2bf(acc[mi][0]);
                    Lw[(ol + 1) * 108 + r] = f2bf(acc[mi][1]);
                    Lw[(ol + 2) * 108 + r] = f2bf(acc[mi][2]);
                    Lw[(ol + 3) * 108 + r] = f2bf(acc[mi][3]);
                }
            }
            __syncthreads();
            for (int i = tid; i < 64 * 25; i += 256) {
                int ol = i / 25, mc = i % 25;
                s16x4 pk = *(const s16x4*)(Lw + ol * 108 + mc * 4);
                *(s16x4*)(yt + (size_t)(n * 256 + o0 + ol) * VT_ + m0 + mc * 4) = pk;
            }
        }
    }
}

// ---------------- finalize per-channel stats -> scale/shift arrays ----------------
__global__ __launch_bounds__(256) void k_stats(const float* __restrict__ psum,
        const float* __restrict__ psq, const float* __restrict__ gamma,
        const float* __restrict__ beta, float* __restrict__ bns,
        float* __restrict__ bnb) {
    int o = blockIdx.x;
    float s = 0.f, q = 0.f;
    for (int i = threadIdx.x; i < 2048; i += 256) {
        s += psum[(size_t)o*2048+i]; q += psq[(size_t)o*2048+i];
    }
    __shared__ float rs[256], rq[256];
    rs[threadIdx.x] = s; rq[threadIdx.x] = q;
    __syncthreads();
    for (int st = 128; st > 0; st >>= 1) {
        if (threadIdx.x < st) { rs[threadIdx.x] += rs[threadIdx.x+st]; rq[threadIdx.x] += rq[threadIdx.x+st]; }
        __syncthreads();
    }
    if (threadIdx.x == 0) {
        float mean = rs[0] / NVTF_;
        float var = rq[0] / NVTF_ - mean * mean;
        float scale = gamma[o] * rsqrtf(var + 1e-5f);
        bns[o] = scale;
        bnb[o] = beta[o] - mean * scale;
    }
}

// ---------------- final BN+ReLU + (t,v)->(v,t) transpose: y3 [O][m'] -> fp32 xout ----------------
__global__ __launch_bounds__(256) void k_bnf(const ushort_t* __restrict__ y3,
        const float* __restrict__ bns, const float* __restrict__ bnb,
        float* __restrict__ xout) {
    __shared__ __align__(16) ushort_t L[8 * VT_];
    int n = blockIdx.y, oc = blockIdx.x;   // 64 x 32
    size_t base = (size_t)(n * 256 + oc * 8) * VT_;
    for (int i = threadIdx.x; i < 3200; i += 256)
        gload16(y3 + base + (size_t)i * 8, (char*)L + i * 16);
    __syncthreads();
    for (int i = threadIdx.x; i < 6400; i += 256) {
        int t4 = i & 31, v = (i >> 5) % 25, o = i / 800;
        int og = oc * 8 + o;
        float sc = bns[og], sh = bnb[og];
        int lb = o * VT_ + v;
        float4 f;
        f.x = fmaxf(fmaf(bf2f(L[lb + (t4*4+0)*25]), sc, sh), 0.f);
        f.y = fmaxf(fmaf(bf2f(L[lb + (t4*4+1)*25]), sc, sh), 0.f);
        f.z = fmaxf(fmaf(bf2f(L[lb + (t4*4+2)*25]), sc, sh), 0.f);
        f.w = fmaxf(fmaf(bf2f(L[lb + (t4*4+3)*25]), sc, sh), 0.f);
        *(float4*)(xout + (size_t)(n * 256 + og) * VT_ + v * T_ + t4 * 4) = f;
    }
}

extern "C" void kernel_launch(void* const* d_in, const int* in_sizes, int n_in,
                              void* d_out, int out_size, void* d_ws, size_t ws_size,
                              hipStream_t stream) {
    const float* x   = (const float*)d_in[0];
    const float* wg1 = (const float*)d_in[1];
    const float* wg2 = (const float*)d_in[2];
    const float* w11 = (const float*)d_in[3];
    const float* w12 = (const float*)d_in[4];
    const float* ga1 = (const float*)d_in[5];
    const float* be1 = (const float*)d_in[6];
    const float* w21 = (const float*)d_in[7];
    const float* w22 = (const float*)d_in[8];
    const float* ga2 = (const float*)d_in[9];
    const float* be2 = (const float*)d_in[10];
    const float* w31 = (const float*)d_in[11];
    const float* w32 = (const float*)d_in[12];
    const float* ga3 = (const float*)d_in[13];
    const float* be3 = (const float*)d_in[14];

    float* xout = (float*)d_out;               // (64,256,25,128) fp32
    float* gout = xout + 52428800;             // (64,128,25,25) fp32

    float* ws = (float*)d_ws;
    ushort_t* xb  = (ushort_t*)(ws + 0);          // 13,107,200 us [v*T+t][64]
    ushort_t* a1  = (ushort_t*)(ws + 6553600);    // 3,276,800 us
    ushort_t* a2  = (ushort_t*)(ws + 8192000);    // 3,276,800 us
    ushort_t* y1  = (ushort_t*)(ws + 9830400);    // 13,107,200 us [m'][64]
    ushort_t* y2  = (ushort_t*)(ws + 16384000);   // 26,214,400 us [m'][128]
    ushort_t* y3  = (ushort_t*)(ws + 29491200);   // 52,428,800 us [O=256][m']
    ushort_t* gb  = (ushort_t*)(ws + 55705600);   // 6,553,600 us [n][t][v][32]
    float* psum = ws + 58982400;                  // 524,288 fl [o][2048]
    float* psq  = ws + 59506688;                  // 524,288 fl
    ushort_t* Wc = (ushort_t*)(ws + 60030976);    // 90,112 us
    float* bns  = ws + 60076032;                  // 256 fl
    float* bnb  = ws + 60076288;                  // 256 fl
    ushort_t* Wc1 = Wc, *Wc2 = Wc + 8192, *Wc3 = Wc + 24576;

    k_a<<<1600, 128, 0, stream>>>(x, wg1, wg2, a1, a2, xb,
                                  w11, w12, w21, w22, w31, w32, Wc);
    k_g<<<512, 256, 0, stream>>>(a1, a2, gout, gb);

    // layer 1: C=64 -> O=64 (xb source, no BN)
    k_fgemm<64, false, true, 0, 1><<<dim3(32, 64), 256, 0, stream>>>(
        Wc1, xb, gb, nullptr, nullptr, y1, psum, psq);
    k_stats<<<64, 256, 0, stream>>>(psum, psq, ga1, be1, bns, bnb);

    // layer 2: C=64 -> O=128 (BN(y1) fused)
    k_fgemm<64, true, false, 0, 2><<<dim3(32, 64), 256, 0, stream>>>(
        Wc2, y1, gb, bns, bnb, y2, psum, psq);
    k_stats<<<128, 256, 0, stream>>>(psum, psq, ga2, be2, bns, bnb);

    // layer 3: C=128 -> O=256 (BN(y2) fused), output [O][m'] via coalesced restage
    k_fgemm<128, true, false, 2, 4><<<dim3(32, 64), 256, 0, stream>>>(
        Wc3, y2, gb, bns, bnb, y3, psum, psq);
    k_stats<<<256, 256, 0, stream>>>(psum, psq, ga3, be3, bns, bnb);

    k_bnf<<<dim3(32, 64), 256, 0, stream>>>(y3, bns, bnb, xout);
}

// Round 11
// 292.148 us; speedup vs baseline: 1.2358x; 1.1903x over previous
//
#include <hip/hip_runtime.h>
#include <cstdint>

#define V_ 25
#define T_ 128
#define VT_ 3200
#define NVTF_ 204800.0f

typedef unsigned short ushort_t;
typedef __attribute__((ext_vector_type(8))) short s16x8;
typedef __attribute__((ext_vector_type(4))) float f32x4;

#define SW(r, ch) ((ch) ^ ((r) & 7) ^ (((r) >> 3) & 7))

__device__ __forceinline__ ushort_t f2bf(float f) {
    union { float f; unsigned u; } v; v.f = f;
    unsigned r = v.u + 0x7FFFu + ((v.u >> 16) & 1u);
    return (ushort_t)(r >> 16);
}
__device__ __forceinline__ float bf2f(ushort_t h) {
    union { unsigned u; float f; } v; v.u = ((unsigned)h) << 16;
    return v.f;
}
__device__ __forceinline__ unsigned cvtpk(float lo, float hi) {
    unsigned r;
    asm volatile("v_cvt_pk_bf16_f32 %0, %1, %2" : "=v"(r) : "v"(lo), "v"(hi));
    return r;
}
__device__ __forceinline__ void gload16(const void* g, void* l) {
    __builtin_amdgcn_global_load_lds((const __attribute__((address_space(1))) void*)g,
                                     (__attribute__((address_space(3))) void*)l, 16, 0, 0);
}

// ---------------- k_a: a1/a2 = wg @ x + xb bf16 [v*T+t][64] + fused wcat ----------------
__global__ __launch_bounds__(128) void k_a(const float* __restrict__ x,
        const float* __restrict__ wg1, const float* __restrict__ wg2,
        ushort_t* __restrict__ a1, ushort_t* __restrict__ a2,
        ushort_t* __restrict__ xb,
        const float* __restrict__ w11, const float* __restrict__ w12,
        const float* __restrict__ w21, const float* __restrict__ w22,
        const float* __restrict__ w31, const float* __restrict__ w32,
        ushort_t* __restrict__ Wc) {
    int b = blockIdx.x; int n = b / V_; int v = b % V_;
    int t = threadIdx.x;
    int wi = b * 128 + t;
    if (wi < 90112) {
        float wv;
        if (wi < 8192) {
            int o = wi >> 7, k = wi & 127;
            wv = (k < 64) ? w11[o * 64 + k] : w12[o * 64 + k - 64];
        } else if (wi < 24576) {
            int j = wi - 8192; int o = j >> 7, k = j & 127;
            wv = (k < 64) ? w21[o * 64 + k] : w22[o * 64 + k - 64];
        } else {
            int j = wi - 24576; int o = j >> 8, k = j & 255;
            wv = (k < 128) ? w31[o * 128 + k] : w32[o * 128 + k - 128];
        }
        Wc[wi] = f2bf(wv);
    }
    __shared__ float w1s[1024], w2s[1024];
    for (int i = threadIdx.x; i < 1024; i += 128) { w1s[i] = wg1[i]; w2s[i] = wg2[i]; }
    __syncthreads();
    float s1[16], s2[16];
    #pragma unroll
    for (int o = 0; o < 16; o++) { s1[o] = 0.f; s2[o] = 0.f; }
    s16x8 xs[8];
    const float* xp = x + (size_t)n * 204800 + v * T_ + t;
    #pragma unroll
    for (int c = 0; c < 64; c++) {
        float xv = xp[(size_t)c * VT_];
        xs[c >> 3][c & 7] = (short)f2bf(xv);
        #pragma unroll
        for (int o = 0; o < 16; o++) {
            s1[o] = fmaf(w1s[o*64+c], xv, s1[o]);
            s2[o] = fmaf(w2s[o*64+c], xv, s2[o]);
        }
    }
    size_t abase = (size_t)n * 51200 + v * T_ + t;
    #pragma unroll
    for (int o = 0; o < 16; o++) {
        a1[abase + (size_t)o * VT_] = f2bf(s1[o]);
        a2[abase + (size_t)o * VT_] = f2bf(s2[o]);
    }
    ushort_t* cp = xb + (size_t)(n * VT_ + v * T_ + t) * 64;
    #pragma unroll
    for (int ch = 0; ch < 8; ch++) *(s16x8*)(cp + ch * 8) = xs[ch];
}

// ---------------- k_g: softmax g, fp32 (d_out) + bf16 copy [n][t][v][32], pad zeroed ----------------
__global__ __launch_bounds__(256) void k_g(const ushort_t* __restrict__ a1,
        const ushort_t* __restrict__ a2, float* __restrict__ g,
        ushort_t* __restrict__ gb) {
    int n = blockIdx.x >> 3; int t0 = (blockIdx.x & 7) * 16;
    __shared__ float A1s[6400], A2s[6400]; // [o][v][tt]
    for (int i = threadIdx.x; i < 6400; i += 256) {
        int o = i / 400; int r = i % 400; int v = r >> 4; int tt = r & 15;
        size_t ga = (size_t)n * 51200 + (size_t)o * VT_ + v * T_ + t0 + tt;
        A1s[i] = bf2f(a1[ga]);
        A2s[i] = bf2f(a2[ga]);
    }
    __syncthreads();
    for (int r = threadIdx.x; r < 400; r += 256) {
        int v = r >> 4; int tt = r & 15;
        float a1r[16];
        #pragma unroll
        for (int o = 0; o < 16; o++) a1r[o] = A1s[o*400 + v*16 + tt];
        float gr[25];
        float mx = -1e30f;
        for (int u = 0; u < 25; u++) {
            float s = 0.f;
            #pragma unroll
            for (int o = 0; o < 16; o++) s = fmaf(a1r[o], A2s[o*400 + u*16 + tt], s);
            gr[u] = s; mx = fmaxf(mx, s);
        }
        float sum = 0.f;
        for (int u = 0; u < 25; u++) { gr[u] = __expf(gr[u] - mx); sum += gr[u]; }
        float inv = 1.f / sum;
        float* gp = g + ((size_t)(n * T_ + t0 + tt) * V_ + v) * V_;
        ushort_t* gbp = gb + ((size_t)((n * 128 + t0 + tt) * 25 + v)) * 32;
        for (int u = 0; u < 25; u++) {
            float val = gr[u] * inv;
            gp[u] = val;
            gbp[u] = f2bf(val);
        }
        #pragma unroll
        for (int u = 25; u < 32; u++) gbp[u] = 0;   // zero K-pad for MFMA-MP
    }
}

// ---------------- fused [BN+ReLU] + MFMA-MP + MFMA GEMM, TG=4, MROWS=100 ----------------
template<int C, bool BNB, bool XBSRC, int TOUT, int OPASS>
__global__ __launch_bounds__(256) void k_fgemm(
        const ushort_t* __restrict__ Wc, const ushort_t* __restrict__ ysrc,
        const ushort_t* __restrict__ gb,
        const float* __restrict__ bns, const float* __restrict__ bnb,
        ushort_t* __restrict__ yt,
        float* __restrict__ psum, float* __restrict__ psq) {
    constexpr int K2 = 2 * C;
    constexpr int KSTEPS = K2 / 32;   // 4 or 8
    constexpr int NC8 = C / 8;        // 8 or 16
    constexpr int NCT = C / 16;       // 4 or 8 c-tiles for MP
    constexpr int HKS = C / 32;       // 2 or 4
    constexpr int MROWS = 100;
    constexpr int MI = 7;
    constexpr int XBYTES = (TOUT == 0) ? 14400 : 16;
    __shared__ __align__(16) ushort_t YS[MROWS * C];
    __shared__ __align__(16) ushort_t MPo[MROWS * C];
    __shared__ __align__(16) char XTRA[XBYTES];
    ushort_t* Lw = (ushort_t*)XTRA;    // TOUT==0 epilogue restage

    int n = blockIdx.y, mb = blockIdx.x;
    int m0 = mb * MROWS, tb = mb * 4;
    int tid = threadIdx.x, w = tid >> 6, lane = tid & 63;
    int l15 = lane & 15, g4 = lane >> 4;

    // ---- stage Y (+BN+ReLU) -> YS swizzled ----
    for (int i = tid; i < MROWS * NC8; i += 256) {
        int yr = i / NC8, cc = i % NC8;
        size_t saddr;
        if (XBSRC) {
            int t = tb + yr / 25, v = yr % 25;
            saddr = (size_t)n * 204800 + (size_t)(v * 128 + t) * 64 + cc * 8;
        } else {
            saddr = ((size_t)n * VT_ + m0 + yr) * C + cc * 8;
        }
        s16x8 vv = *(const s16x8*)(ysrc + saddr);
        if (BNB) {
            int ob = cc * 8;
            float4 s0 = *(const float4*)(bns + ob), s1 = *(const float4*)(bns + ob + 4);
            float4 h0 = *(const float4*)(bnb + ob), h1 = *(const float4*)(bnb + ob + 4);
            float sc[8] = {s0.x, s0.y, s0.z, s0.w, s1.x, s1.y, s1.z, s1.w};
            float sh[8] = {h0.x, h0.y, h0.z, h0.w, h1.x, h1.y, h1.z, h1.w};
            float ff[8];
            #pragma unroll
            for (int j = 0; j < 8; j++)
                ff[j] = fmaxf(fmaf(bf2f((ushort_t)vv[j]), sc[j], sh[j]), 0.f);
            union { unsigned u[4]; s16x8 s; } U;
            U.u[0] = cvtpk(ff[0], ff[1]); U.u[1] = cvtpk(ff[2], ff[3]);
            U.u[2] = cvtpk(ff[4], ff[5]); U.u[3] = cvtpk(ff[6], ff[7]);
            vv = U.s;
        }
        *(s16x8*)(YS + ((size_t)yr * NC8 + SW(yr, cc)) * 8) = vv;
    }
    __syncthreads();
    // ---- MFMA message passing: D[v][c] = sum_u G[v][u] * Y[u][c], per t (wave=tl) ----
    {
        int tl = w;
        const ushort_t* gbase = gb + ((size_t)((n * 128 + tb + tl) * 25)) * 32;
        // A = G fragments (2 v-tiles), per-lane global 16B loads (L2/L3-resident)
        s16x8 aG0 = *(const s16x8*)(gbase + (size_t)(l15) * 32 + g4 * 8);
        s16x8 aG1 = *(const s16x8*)(gbase + (size_t)(16 + l15) * 32 + g4 * 8);
        #pragma unroll
        for (int ct = 0; ct < NCT; ct++) {
            int c = ct * 16 + l15;
            int cc = c >> 3, sub = c & 7;
            s16x8 bF;
            #pragma unroll
            for (int j = 0; j < 8; j++) {
                int u = g4 * 8 + j;
                int uu = (u > 24) ? 24 : u;         // clamp; A=0 kills u>=25
                int r = tl * 25 + uu;
                bF[j] = (short)YS[((size_t)r * NC8 + SW(r, cc)) * 8 + sub];
            }
            f32x4 z = {};
            f32x4 d0 = __builtin_amdgcn_mfma_f32_16x16x32_bf16(aG0, bF, z, 0, 0, 0);
            f32x4 d1 = __builtin_amdgcn_mfma_f32_16x16x32_bf16(aG1, bF, z, 0, 0, 0);
            #pragma unroll
            for (int b = 0; b < 4; b++) {
                int v0 = g4 * 4 + b;
                int r0 = tl * 25 + v0;
                MPo[((size_t)r0 * NC8 + SW(r0, cc)) * 8 + sub] = f2bf(d0[b]);
                int v1 = 16 + g4 * 4 + b;
                if (v1 < 25) {
                    int r1 = tl * 25 + v1;
                    MPo[((size_t)r1 * NC8 + SW(r1, cc)) * 8 + sub] = f2bf(d1[b]);
                }
            }
        }
    }
    __syncthreads();
    // ---- o-pass sweep: A in registers, MFMA, stats, epilogue ----
    for (int pass = 0; pass < OPASS; pass++) {
        int o0 = pass * 64;
        s16x8 aReg[KSTEPS];
        const ushort_t* ap = Wc + (size_t)(o0 + w * 16 + l15) * K2 + g4 * 8;
        #pragma unroll
        for (int ks = 0; ks < KSTEPS; ks++)
            aReg[ks] = *(const s16x8*)(ap + ks * 32);
        f32x4 acc[MI] = {};
        __builtin_amdgcn_s_setprio(1);
        #pragma unroll
        for (int ks = 0; ks < KSTEPS; ks++) {
            const ushort_t* bbase = (ks < HKS) ? MPo : YS;
            int ksl = (ks < HKS) ? ks : ks - HKS;
            #pragma unroll
            for (int mi = 0; mi < MI; mi++) {
                int r = mi * 16 + l15;
                int rr = (r < MROWS) ? r : (MROWS - 1);
                int ch = ksl * 4 + g4;
                s16x8 bF = *(const s16x8*)(bbase + ((size_t)rr * NC8 + SW(rr, ch)) * 8);
                acc[mi] = __builtin_amdgcn_mfma_f32_16x16x32_bf16(aReg[ks], bF, acc[mi], 0, 0, 0);
            }
        }
        __builtin_amdgcn_s_setprio(0);
        // BN partial stats (mask pad rows >= 100: mi==6 && l15>=4)
        int p = n * 32 + mb;
        #pragma unroll
        for (int b = 0; b < 4; b++) {
            float ss = 0.f, qq = 0.f;
            #pragma unroll
            for (int mi = 0; mi < MI; mi++) {
                float v0 = acc[mi][b];
                if (mi == 6 && l15 >= 4) v0 = 0.f;
                ss += v0; qq = fmaf(v0, v0, qq);
            }
            #pragma unroll
            for (int msk = 1; msk < 16; msk <<= 1) {
                ss += __shfl_xor(ss, msk, 16);
                qq += __shfl_xor(qq, msk, 16);
            }
            if (l15 == 0) {
                int o = o0 + w * 16 + g4 * 4 + b;
                psum[(size_t)o * 2048 + p] = ss;
                psq [(size_t)o * 2048 + p] = qq;
            }
        }
        if (TOUT == 0) {
            __syncthreads();
            #pragma unroll
            for (int mi = 0; mi < MI; mi++) {
                int r = mi * 16 + l15;
                if (r < MROWS) {
                    unsigned lo = cvtpk(acc[mi][0], acc[mi][1]);
                    unsigned hi = cvtpk(acc[mi][2], acc[mi][3]);
                    *(unsigned*)(Lw + r * 72 + w * 16 + g4 * 4)     = lo;
                    *(unsigned*)(Lw + r * 72 + w * 16 + g4 * 4 + 2) = hi;
                }
            }
            __syncthreads();
            for (int i = tid; i < MROWS * 8; i += 256) {
                int r = i >> 3, oc = i & 7;
                s16x8 pk = *(const s16x8*)(Lw + r * 72 + oc * 8);
                *(s16x8*)(yt + ((size_t)n * VT_ + m0 + r) * (OPASS * 64) + o0 + oc * 8) = pk;
            }
        } else {
            // direct scalar stores (round-8 proven path; L2/L3 absorbs)
            int obase = n * 256 + o0 + w * 16 + g4 * 4;
            #pragma unroll
            for (int mi = 0; mi < MI; mi++) {
                int r = mi * 16 + l15;
                if (r < MROWS) {
                    #pragma unroll
                    for (int b = 0; b < 4; b++)
                        yt[(size_t)(obase + b) * VT_ + m0 + r] = f2bf(acc[mi][b]);
                }
            }
        }
    }
}

// ---------------- finalize per-channel stats -> scale/shift arrays ----------------
__global__ __launch_bounds__(256) void k_stats(const float* __restrict__ psum,
        const float* __restrict__ psq, const float* __restrict__ gamma,
        const float* __restrict__ beta, float* __restrict__ bns,
        float* __restrict__ bnb) {
    int o = blockIdx.x;
    float s = 0.f, q = 0.f;
    for (int i = threadIdx.x; i < 2048; i += 256) {
        s += psum[(size_t)o*2048+i]; q += psq[(size_t)o*2048+i];
    }
    __shared__ float rs[256], rq[256];
    rs[threadIdx.x] = s; rq[threadIdx.x] = q;
    __syncthreads();
    for (int st = 128; st > 0; st >>= 1) {
        if (threadIdx.x < st) { rs[threadIdx.x] += rs[threadIdx.x+st]; rq[threadIdx.x] += rq[threadIdx.x+st]; }
        __syncthreads();
    }
    if (threadIdx.x == 0) {
        float mean = rs[0] / NVTF_;
        float var = rq[0] / NVTF_ - mean * mean;
        float scale = gamma[o] * rsqrtf(var + 1e-5f);
        bns[o] = scale;
        bnb[o] = beta[o] - mean * scale;
    }
}

// ---------------- final BN+ReLU + (t,v)->(v,t) transpose: y3 [O][m'] -> fp32 xout ----------------
__global__ __launch_bounds__(256) void k_bnf(const ushort_t* __restrict__ y3,
        const float* __restrict__ bns, const float* __restrict__ bnb,
        float* __restrict__ xout) {
    __shared__ __align__(16) ushort_t L[8 * VT_];
    int n = blockIdx.y, oc = blockIdx.x;   // 64 x 32
    size_t base = (size_t)(n * 256 + oc * 8) * VT_;
    for (int i = threadIdx.x; i < 3200; i += 256)
        gload16(y3 + base + (size_t)i * 8, (char*)L + i * 16);
    __syncthreads();
    for (int i = threadIdx.x; i < 6400; i += 256) {
        int t4 = i & 31, v = (i >> 5) % 25, o = i / 800;
        int og = oc * 8 + o;
        float sc = bns[og], sh = bnb[og];
        int lb = o * VT_ + v;
        float4 f;
        f.x = fmaxf(fmaf(bf2f(L[lb + (t4*4+0)*25]), sc, sh), 0.f);
        f.y = fmaxf(fmaf(bf2f(L[lb + (t4*4+1)*25]), sc, sh), 0.f);
        f.z = fmaxf(fmaf(bf2f(L[lb + (t4*4+2)*25]), sc, sh), 0.f);
        f.w = fmaxf(fmaf(bf2f(L[lb + (t4*4+3)*25]), sc, sh), 0.f);
        *(float4*)(xout + (size_t)(n * 256 + og) * VT_ + v * T_ + t4 * 4) = f;
    }
}

extern "C" void kernel_launch(void* const* d_in, const int* in_sizes, int n_in,
                              void* d_out, int out_size, void* d_ws, size_t ws_size,
                              hipStream_t stream) {
    const float* x   = (const float*)d_in[0];
    const float* wg1 = (const float*)d_in[1];
    const float* wg2 = (const float*)d_in[2];
    const float* w11 = (const float*)d_in[3];
    const float* w12 = (const float*)d_in[4];
    const float* ga1 = (const float*)d_in[5];
    const float* be1 = (const float*)d_in[6];
    const float* w21 = (const float*)d_in[7];
    const float* w22 = (const float*)d_in[8];
    const float* ga2 = (const float*)d_in[9];
    const float* be2 = (const float*)d_in[10];
    const float* w31 = (const float*)d_in[11];
    const float* w32 = (const float*)d_in[12];
    const float* ga3 = (const float*)d_in[13];
    const float* be3 = (const float*)d_in[14];

    float* xout = (float*)d_out;               // (64,256,25,128) fp32
    float* gout = xout + 52428800;             // (64,128,25,25) fp32

    float* ws = (float*)d_ws;
    ushort_t* xb  = (ushort_t*)(ws + 0);          // 13,107,200 us [v*T+t][64]
    ushort_t* a1  = (ushort_t*)(ws + 6553600);    // 3,276,800 us
    ushort_t* a2  = (ushort_t*)(ws + 8192000);    // 3,276,800 us
    ushort_t* y1  = (ushort_t*)(ws + 9830400);    // 13,107,200 us [m'][64]
    ushort_t* y2  = (ushort_t*)(ws + 16384000);   // 26,214,400 us [m'][128]
    ushort_t* y3  = (ushort_t*)(ws + 29491200);   // 52,428,800 us [O=256][m']
    ushort_t* gb  = (ushort_t*)(ws + 55705600);   // 6,553,600 us [n][t][v][32]
    float* psum = ws + 58982400;                  // 524,288 fl [o][2048]
    float* psq  = ws + 59506688;                  // 524,288 fl
    ushort_t* Wc = (ushort_t*)(ws + 60030976);    // 90,112 us
    float* bns  = ws + 60076032;                  // 256 fl
    float* bnb  = ws + 60076288;                  // 256 fl
    ushort_t* Wc1 = Wc, *Wc2 = Wc + 8192, *Wc3 = Wc + 24576;

    k_a<<<1600, 128, 0, stream>>>(x, wg1, wg2, a1, a2, xb,
                                  w11, w12, w21, w22, w31, w32, Wc);
    k_g<<<512, 256, 0, stream>>>(a1, a2, gout, gb);

    // layer 1: C=64 -> O=64 (xb source, no BN)
    k_fgemm<64, false, true, 0, 1><<<dim3(32, 64), 256, 0, stream>>>(
        Wc1, xb, gb, nullptr, nullptr, y1, psum, psq);
    k_stats<<<64, 256, 0, stream>>>(psum, psq, ga1, be1, bns, bnb);

    // layer 2: C=64 -> O=128 (BN(y1) fused)
    k_fgemm<64, true, false, 0, 2><<<dim3(32, 64), 256, 0, stream>>>(
        Wc2, y1, gb, bns, bnb, y2, psum, psq);
    k_stats<<<128, 256, 0, stream>>>(psum, psq, ga2, be2, bns, bnb);

    // layer 3: C=128 -> O=256 (BN(y2) fused), output [O][m'] direct stores
    k_fgemm<128, true, false, 2, 4><<<dim3(32, 64), 256, 0, stream>>>(
        Wc3, y2, gb, bns, bnb, y3, psum, psq);
    k_stats<<<256, 256, 0, stream>>>(psum, psq, ga3, be3, bns, bnb);

    k_bnf<<<dim3(32, 64), 256, 0, stream>>>(y3, bns, bnb, xout);
}